// Round 4
// baseline (555.948 us; speedup 1.0000x reference)
//
#include <hip/hip_runtime.h>
#include <hip/hip_bf16.h>

#define VOUT 50257
#define KHOT 1024
#define DIM  1024
#define RHOT 384
#define RCOLD 32
#define RF   416   // RHOT + RCOLD

typedef __attribute__((ext_vector_type(8))) short short8;
typedef __attribute__((ext_vector_type(4))) float f32x4;

// ---------------- K0: convert f32 weights to bf16 ----------------
__global__ void k_convert(const float* __restrict__ Bh, const float* __restrict__ Bc,
                          const float* __restrict__ Uh, const float* __restrict__ Uc,
                          __hip_bfloat16* __restrict__ Bmat,
                          __hip_bfloat16* __restrict__ UhB,
                          __hip_bfloat16* __restrict__ UcB) {
  const int nBh = RHOT * DIM;            // 393216
  const int nBm = RF * DIM;              // 425984
  const int nUh = KHOT * RHOT;           // 393216
  const int nUc = (VOUT - KHOT) * RCOLD; // 1575456
  const int total = nBm + nUh + nUc;
  for (int i = blockIdx.x * blockDim.x + threadIdx.x; i < total;
       i += gridDim.x * blockDim.x) {
    if (i < nBm) {
      float v = (i < nBh) ? Bh[i] : Bc[i - nBh];
      Bmat[i] = __float2bfloat16(v);
    } else if (i < nBm + nUh) {
      UhB[i - nBm] = __float2bfloat16(Uh[i - nBm]);
    } else {
      int j = i - nBm - nUh;
      UcB[j] = __float2bfloat16(Uc[j]);
    }
  }
}

// ---------------- K1: G = Bmat @ Bmat^T  (416x416, K=1024), f32 out ----------------
__global__ __launch_bounds__(256) void k_gram(const __hip_bfloat16* __restrict__ Bmat,
                                              float* __restrict__ G) {
  const int wave = threadIdx.x >> 6;
  const int lane = threadIdx.x & 63;
  const int idx = blockIdx.x * 4 + wave;
  if (idx >= 26 * 26) return;  // wave-uniform
  const int ti = idx / 26, tj = idx % 26;
  const int i0 = ti * 16, j0 = tj * 16;
  const int col16 = lane & 15;
  const int g4 = lane >> 4;

  f32x4 acc = (f32x4){0.f, 0.f, 0.f, 0.f};
  const __hip_bfloat16* arow = Bmat + (size_t)(i0 + col16) * DIM;
  const __hip_bfloat16* brow = Bmat + (size_t)(j0 + col16) * DIM;
#pragma unroll 4
  for (int ks = 0; ks < DIM / 32; ++ks) {
    short8 a = *reinterpret_cast<const short8*>(arow + ks * 32 + g4 * 8);
    short8 b = *reinterpret_cast<const short8*>(brow + ks * 32 + g4 * 8);
    acc = __builtin_amdgcn_mfma_f32_16x16x32_bf16(a, b, acc, 0, 0, 0);
  }
#pragma unroll
  for (int r = 0; r < 4; ++r)
    G[(size_t)(i0 + g4 * 4 + r) * RF + j0 + col16] = acc[r];
}

// ---------------- K2: per-token F[n] = u @ G  (f32 math, bf16 out) ----------------
__global__ void k_encode(const int* __restrict__ tokens, const int* __restrict__ o2n,
                         const float* __restrict__ Uh, const float* __restrict__ Uc,
                         const float* __restrict__ G, __hip_bfloat16* __restrict__ F) {
  const int n = blockIdx.x;
  __shared__ float u[RHOT];
  const int tok = tokens[n];
  const int tn = o2n[tok];
  const bool hot = tn < KHOT;
  const int R = hot ? RHOT : RCOLD;
  const float* urow = hot ? (Uh + (size_t)tn * RHOT) : (Uc + (size_t)(tn - KHOT) * RCOLD);
  for (int r = threadIdx.x; r < R; r += blockDim.x) u[r] = urow[r];
  __syncthreads();
  const int gbase = hot ? 0 : RHOT;
  for (int c = threadIdx.x; c < RF; c += blockDim.x) {
    float acc = 0.f;
    for (int r = 0; r < R; ++r) acc += u[r] * G[(size_t)(gbase + r) * RF + c];
    F[(size_t)n * RF + c] = __float2bfloat16(acc);
  }
}

// ---------------- K3 v4: 64 rows x 1024 cols per block, barrier-free epilogue ----------------
// 4 waves; wave w owns contiguous cols [bx*1024 + w*256, +256).
// Per 16-row chunk t: compute 16 MFMA subtiles (acc[16]), then transpose via a
// PRIVATE per-wave LDS buffer (no __syncthreads -> no vmcnt store drains), store
// dword-per-lane runs: 256B contiguous per instruction, 1KB per row per wave,
// 4KB per row per block, temporally batched -> L2 merges misaligned boundaries.
#define CPB 1024
#define WCOL 256
#define RPB 64

__global__ __launch_bounds__(256) void k_out(const int* __restrict__ o2n,
                                             const __hip_bfloat16* __restrict__ F,
                                             const __hip_bfloat16* __restrict__ Uh,
                                             const __hip_bfloat16* __restrict__ Uc,
                                             const float* __restrict__ log_alpha,
                                             const float* __restrict__ bias,
                                             float* __restrict__ out) {
  __shared__ float Epi[4][16][132];  // per-wave [16 rows][128 cols + pad 4]
  const int tid = threadIdx.x;
  const int wave = tid >> 6;
  const int lane = tid & 63;
  const int col16 = lane & 15;
  const int g4 = lane >> 4;
  const int n0 = blockIdx.y * RPB;
  const int wcol0 = blockIdx.x * CPB + wave * WCOL;
  const float alpha = expf(log_alpha[0]);
  const short8 zero8 = (short8){0, 0, 0, 0, 0, 0, 0, 0};

  // per-col-subtile metadata (16 subtiles of 16 cols each)
  int srcs[16];
  unsigned hotmask = 0, coldmask = 0;
#pragma unroll
  for (int sub = 0; sub < 16; ++sub) {
    const int v = wcol0 + sub * 16 + col16;
    const int vc = (v < VOUT) ? v : (VOUT - 1);
    srcs[sub] = o2n[vc];
    if (__any(srcs[sub] < KHOT)) hotmask |= (1u << sub);
    if (__any(srcs[sub] >= KHOT)) coldmask |= (1u << sub);
  }
  // per-lane bias for the 4 store slots (64 cols apart)
  float bj[4];
#pragma unroll
  for (int j = 0; j < 4; ++j) {
    const int c = wcol0 + j * 64 + lane;
    bj[j] = (c < VOUT) ? bias[c] : 0.f;
  }

  for (int t = 0; t < 4; ++t) {
    f32x4 acc[16];
#pragma unroll
    for (int sub = 0; sub < 16; ++sub) acc[sub] = (f32x4){0.f, 0.f, 0.f, 0.f};

    // cold contribution: K = 32, A-frag direct from global F (L2-resident)
    {
      const short8 afc = *reinterpret_cast<const short8*>(
          F + (size_t)(n0 + t * 16 + col16) * RF + RHOT + g4 * 8);
#pragma unroll
      for (int sub = 0; sub < 16; ++sub) {
        if (coldmask & (1u << sub)) {
          short8 bfrag = zero8;
          if (srcs[sub] >= KHOT)
            bfrag = *reinterpret_cast<const short8*>(
                Uc + (size_t)(srcs[sub] - KHOT) * RCOLD + g4 * 8);
          acc[sub] = __builtin_amdgcn_mfma_f32_16x16x32_bf16(afc, bfrag, acc[sub], 0, 0, 0);
        }
      }
    }
    // hot contribution: K = 384 (only blocks containing hot columns)
    if (hotmask) {
      for (int ks = 0; ks < RHOT / 32; ++ks) {
        const short8 afh = *reinterpret_cast<const short8*>(
            F + (size_t)(n0 + t * 16 + col16) * RF + ks * 32 + g4 * 8);
#pragma unroll
        for (int sub = 0; sub < 16; ++sub) {
          if (hotmask & (1u << sub)) {
            short8 bfrag = zero8;
            if (srcs[sub] < KHOT)
              bfrag = *reinterpret_cast<const short8*>(
                  Uh + (size_t)srcs[sub] * RHOT + ks * 32 + g4 * 8);
            acc[sub] = __builtin_amdgcn_mfma_f32_16x16x32_bf16(afh, bfrag, acc[sub], 0, 0, 0);
          }
        }
      }
    }

    // epilogue: two halves of 128 cols, private LDS transpose, no barriers
#pragma unroll
    for (int half = 0; half < 2; ++half) {
#pragma unroll
      for (int s8 = 0; s8 < 8; ++s8) {
        const int sub = half * 8 + s8;
#pragma unroll
        for (int r = 0; r < 4; ++r)
          Epi[wave][g4 * 4 + r][s8 * 16 + col16] = acc[sub][r];
      }
      asm volatile("s_waitcnt lgkmcnt(0)" ::: "memory");  // RAW: writes visible
#pragma unroll
      for (int row = 0; row < 16; ++row) {
#pragma unroll
        for (int j = 0; j < 2; ++j) {
          const int jj = half * 2 + j;
          const int c = wcol0 + jj * 64 + lane;
          const float val = Epi[wave][row][j * 64 + lane];
          if (c < VOUT)
            out[(size_t)(n0 + t * 16 + row) * VOUT + c] = val * alpha + bj[jj];
        }
      }
      asm volatile("s_waitcnt lgkmcnt(0)" ::: "memory");  // WAR: reads done before reuse
    }
  }
}

extern "C" void kernel_launch(void* const* d_in, const int* in_sizes, int n_in,
                              void* d_out, int out_size, void* d_ws, size_t ws_size,
                              hipStream_t stream) {
  const int* tokens    = (const int*)d_in[0];
  const int* o2n       = (const int*)d_in[1];
  const float* B_hot   = (const float*)d_in[2];
  const float* B_cold  = (const float*)d_in[3];
  const float* U_hot   = (const float*)d_in[4];
  const float* U_cold  = (const float*)d_in[5];
  const float* log_a   = (const float*)d_in[6];
  const float* bias    = (const float*)d_in[7];
  float* out = (float*)d_out;

  const int N = in_sizes[0];  // 4096 tokens

  // workspace layout (bytes)
  char* ws = (char*)d_ws;
  __hip_bfloat16* Bmat = (__hip_bfloat16*)(ws + 0);             // 425984*2
  __hip_bfloat16* UhB  = (__hip_bfloat16*)(ws + (1u << 20));    // 393216*2
  __hip_bfloat16* UcB  = (__hip_bfloat16*)(ws + (2u << 20));    // 1575456*2
  float*          G    = (float*)(ws + (6u << 20));             // 416*416*4
  __hip_bfloat16* F    = (__hip_bfloat16*)(ws + (7u << 20));    // 4096*416*2

  k_convert<<<2048, 256, 0, stream>>>(B_hot, B_cold, U_hot, U_cold, Bmat, UhB, UcB);
  k_gram<<<169, 256, 0, stream>>>(Bmat, G);
  k_encode<<<N, 256, 0, stream>>>(tokens, o2n, U_hot, U_cold, G, F);

  dim3 grid((VOUT + CPB - 1) / CPB, N / RPB);
  k_out<<<grid, 256, 0, stream>>>(o2n, F, UhB, UcB, log_a, bias, out);
}

// Round 5
// 484.046 us; speedup vs baseline: 1.1485x; 1.1485x over previous
//
#include <hip/hip_runtime.h>
#include <hip/hip_bf16.h>

#define VOUT 50257
#define KHOT 1024
#define DIM  1024
#define RHOT 384
#define RCOLD 32
#define RF   416   // RHOT + RCOLD

typedef __attribute__((ext_vector_type(8))) short short8;
typedef __attribute__((ext_vector_type(4))) float f32x4;

// ---------------- K0: convert f32 weights to bf16 ----------------
__global__ void k_convert(const float* __restrict__ Bh, const float* __restrict__ Bc,
                          const float* __restrict__ Uh, const float* __restrict__ Uc,
                          __hip_bfloat16* __restrict__ Bmat,
                          __hip_bfloat16* __restrict__ UhB,
                          __hip_bfloat16* __restrict__ UcB) {
  const int nBh = RHOT * DIM;            // 393216
  const int nBm = RF * DIM;              // 425984
  const int nUh = KHOT * RHOT;           // 393216
  const int nUc = (VOUT - KHOT) * RCOLD; // 1575456
  const int total = nBm + nUh + nUc;
  for (int i = blockIdx.x * blockDim.x + threadIdx.x; i < total;
       i += gridDim.x * blockDim.x) {
    if (i < nBm) {
      float v = (i < nBh) ? Bh[i] : Bc[i - nBh];
      Bmat[i] = __float2bfloat16(v);
    } else if (i < nBm + nUh) {
      UhB[i - nBm] = __float2bfloat16(Uh[i - nBm]);
    } else {
      int j = i - nBm - nUh;
      UcB[j] = __float2bfloat16(Uc[j]);
    }
  }
}

// ---------------- K1: G = Bmat @ Bmat^T  (416x416, K=1024), f32 out ----------------
__global__ __launch_bounds__(256) void k_gram(const __hip_bfloat16* __restrict__ Bmat,
                                              float* __restrict__ G) {
  const int wave = threadIdx.x >> 6;
  const int lane = threadIdx.x & 63;
  const int idx = blockIdx.x * 4 + wave;
  if (idx >= 26 * 26) return;  // wave-uniform
  const int ti = idx / 26, tj = idx % 26;
  const int i0 = ti * 16, j0 = tj * 16;
  const int col16 = lane & 15;
  const int g4 = lane >> 4;

  f32x4 acc = (f32x4){0.f, 0.f, 0.f, 0.f};
  const __hip_bfloat16* arow = Bmat + (size_t)(i0 + col16) * DIM;
  const __hip_bfloat16* brow = Bmat + (size_t)(j0 + col16) * DIM;
#pragma unroll 4
  for (int ks = 0; ks < DIM / 32; ++ks) {
    short8 a = *reinterpret_cast<const short8*>(arow + ks * 32 + g4 * 8);
    short8 b = *reinterpret_cast<const short8*>(brow + ks * 32 + g4 * 8);
    acc = __builtin_amdgcn_mfma_f32_16x16x32_bf16(a, b, acc, 0, 0, 0);
  }
#pragma unroll
  for (int r = 0; r < 4; ++r)
    G[(size_t)(i0 + g4 * 4 + r) * RF + j0 + col16] = acc[r];
}

// ---------------- K2: per-token F[n] = u @ G  (f32 math, bf16 out) ----------------
__global__ void k_encode(const int* __restrict__ tokens, const int* __restrict__ o2n,
                         const float* __restrict__ Uh, const float* __restrict__ Uc,
                         const float* __restrict__ G, __hip_bfloat16* __restrict__ F) {
  const int n = blockIdx.x;
  __shared__ float u[RHOT];
  const int tok = tokens[n];
  const int tn = o2n[tok];
  const bool hot = tn < KHOT;
  const int R = hot ? RHOT : RCOLD;
  const float* urow = hot ? (Uh + (size_t)tn * RHOT) : (Uc + (size_t)(tn - KHOT) * RCOLD);
  for (int r = threadIdx.x; r < R; r += blockDim.x) u[r] = urow[r];
  __syncthreads();
  const int gbase = hot ? 0 : RHOT;
  for (int c = threadIdx.x; c < RF; c += blockDim.x) {
    float acc = 0.f;
    for (int r = 0; r < R; ++r) acc += u[r] * G[(size_t)(gbase + r) * RF + c];
    F[(size_t)n * RF + c] = __float2bfloat16(acc);
  }
}

// ---------------- K3 v5: 64 rows x 1024 cols per block; v3-style strip epilogue ----------------
// Wave w owns 16 col-subtiles {s*256 + w*64 + k*16 : s,k in 0..3}. Per 16-row chunk t,
// per strip s: waves write their 4 subtiles (scaled+biased) into Epi[16][260], sync,
// each wave stores 4 full rows of the strip as 1KB global_store_dwordx4 runs.
// Each output row gets 4KB from one block (strips microseconds apart -> L2 merges
// misaligned boundary lines). XCD-chunked swizzle keeps neighbor col-windows on one XCD.
#define CPB 1024
#define RPB 64

__global__ __launch_bounds__(256) void k_out(const int* __restrict__ o2n,
                                             const __hip_bfloat16* __restrict__ F,
                                             const __hip_bfloat16* __restrict__ Uh,
                                             const __hip_bfloat16* __restrict__ Uc,
                                             const float* __restrict__ log_alpha,
                                             const float* __restrict__ bias,
                                             float* __restrict__ out) {
  __shared__ __hip_bfloat16 Fc[RPB][40];  // cold F slice [64 rows][32 cols], pitch 40
  __shared__ float Epi[16][260];          // strip staging [16 rows][256 cols + pad]
  const int tid = threadIdx.x;
  const int wave = tid >> 6;
  const int lane = tid & 63;
  const int col16 = lane & 15;
  const int g4 = lane >> 4;

  // XCD-chunked swizzle: blocks on XCD x get a contiguous run of tiles (tx fastest)
  const int nx = gridDim.x;                        // 50
  const int L = blockIdx.y * nx + blockIdx.x;
  const int ntot = nx * gridDim.y;                 // 3200 (divisible by 8)
  const int T = (L >> 3) + (L & 7) * (ntot >> 3);
  const int tx = T % nx;
  const int ty = T / nx;
  const int n0 = ty * RPB;
  const int cb = tx * CPB;

  const float alpha = expf(log_alpha[0]);
  const short8 zero8 = (short8){0, 0, 0, 0, 0, 0, 0, 0};

  // stage cold F slice: 64 rows x 32 cols (16B per thread, 256 threads exactly)
  {
    const int row = tid >> 2, chunk = tid & 3;
    short8 v = *reinterpret_cast<const short8*>(F + (size_t)(n0 + row) * RF + RHOT + chunk * 8);
    *reinterpret_cast<short8*>(&Fc[row][chunk * 8]) = v;
  }

  // per-subtile metadata: i = s*4 + k, col base cb + s*256 + wave*64 + k*16
  int srcs[16];
  float bvk[16];
  unsigned hotmask = 0, coldmask = 0;
#pragma unroll
  for (int i = 0; i < 16; ++i) {
    const int s = i >> 2, k = i & 3;
    const int v = cb + s * 256 + wave * 64 + k * 16 + col16;
    const int vc = (v < VOUT) ? v : (VOUT - 1);
    srcs[i] = o2n[vc];
    bvk[i] = bias[vc];
    if (__any(srcs[i] < KHOT)) hotmask |= (1u << i);
    if (__any(srcs[i] >= KHOT)) coldmask |= (1u << i);
  }
  __syncthreads();  // Fc ready

  for (int t = 0; t < 4; ++t) {
    f32x4 acc[16];
#pragma unroll
    for (int i = 0; i < 16; ++i) acc[i] = (f32x4){0.f, 0.f, 0.f, 0.f};

    // cold contribution: K = 32 from LDS (A-frag shared across all 16 subtiles)
    {
      const short8 afc = *reinterpret_cast<const short8*>(&Fc[t * 16 + col16][g4 * 8]);
#pragma unroll
      for (int i = 0; i < 16; ++i) {
        if (coldmask & (1u << i)) {
          short8 bfrag = zero8;
          if (srcs[i] >= KHOT)
            bfrag = *reinterpret_cast<const short8*>(
                Uc + (size_t)(srcs[i] - KHOT) * RCOLD + g4 * 8);
          acc[i] = __builtin_amdgcn_mfma_f32_16x16x32_bf16(afc, bfrag, acc[i], 0, 0, 0);
        }
      }
    }
    // hot contribution: K = 384 (rare: only blocks containing hot columns)
    if (hotmask) {
      for (int ks = 0; ks < RHOT / 32; ++ks) {
        const short8 afh = *reinterpret_cast<const short8*>(
            F + (size_t)(n0 + t * 16 + col16) * RF + ks * 32 + g4 * 8);
#pragma unroll
        for (int i = 0; i < 16; ++i) {
          if (hotmask & (1u << i)) {
            short8 bfrag = zero8;
            if (srcs[i] < KHOT)
              bfrag = *reinterpret_cast<const short8*>(
                  Uh + (size_t)srcs[i] * RHOT + ks * 32 + g4 * 8);
            acc[i] = __builtin_amdgcn_mfma_f32_16x16x32_bf16(afh, bfrag, acc[i], 0, 0, 0);
          }
        }
      }
    }

    // epilogue: 4 strips of 256 cols through the shared Epi buffer
    for (int s = 0; s < 4; ++s) {
#pragma unroll
      for (int k = 0; k < 4; ++k) {
        const int i = s * 4 + k;
#pragma unroll
        for (int r = 0; r < 4; ++r)
          Epi[g4 * 4 + r][wave * 64 + k * 16 + col16] = acc[i][r] * alpha + bvk[i];
      }
      __syncthreads();
#pragma unroll
      for (int rr = 0; rr < 4; ++rr) {
        const int row = wave * 4 + rr;
        f32x4 vals = *reinterpret_cast<const f32x4*>(&Epi[row][lane * 4]);
        const size_t gr = (size_t)(n0 + t * 16 + row) * VOUT;
        const int c0 = cb + s * 256 + lane * 4;
        if (c0 + 3 < VOUT) {
          *reinterpret_cast<f32x4*>(out + gr + c0) = vals;
        } else {
#pragma unroll
          for (int j = 0; j < 4; ++j)
            if (c0 + j < VOUT) out[gr + c0 + j] = vals[j];
        }
      }
      __syncthreads();  // strip reads done before next strip's writes
    }
  }
}

extern "C" void kernel_launch(void* const* d_in, const int* in_sizes, int n_in,
                              void* d_out, int out_size, void* d_ws, size_t ws_size,
                              hipStream_t stream) {
  const int* tokens    = (const int*)d_in[0];
  const int* o2n       = (const int*)d_in[1];
  const float* B_hot   = (const float*)d_in[2];
  const float* B_cold  = (const float*)d_in[3];
  const float* U_hot   = (const float*)d_in[4];
  const float* U_cold  = (const float*)d_in[5];
  const float* log_a   = (const float*)d_in[6];
  const float* bias    = (const float*)d_in[7];
  float* out = (float*)d_out;

  const int N = in_sizes[0];  // 4096 tokens

  // workspace layout (bytes)
  char* ws = (char*)d_ws;
  __hip_bfloat16* Bmat = (__hip_bfloat16*)(ws + 0);             // 425984*2
  __hip_bfloat16* UhB  = (__hip_bfloat16*)(ws + (1u << 20));    // 393216*2
  __hip_bfloat16* UcB  = (__hip_bfloat16*)(ws + (2u << 20));    // 1575456*2
  float*          G    = (float*)(ws + (6u << 20));             // 416*416*4
  __hip_bfloat16* F    = (__hip_bfloat16*)(ws + (7u << 20));    // 4096*416*2

  k_convert<<<2048, 256, 0, stream>>>(B_hot, B_cold, U_hot, U_cold, Bmat, UhB, UcB);
  k_gram<<<169, 256, 0, stream>>>(Bmat, G);
  k_encode<<<N, 256, 0, stream>>>(tokens, o2n, U_hot, U_cold, G, F);

  dim3 grid((VOUT + CPB - 1) / CPB, N / RPB);
  k_out<<<grid, 256, 0, stream>>>(o2n, F, UhB, UcB, log_a, bias, out);
}